// Round 1
// baseline (34.617 us; speedup 1.0000x reference)
//
#include <hip/hip_runtime.h>
#include <hip/hip_bf16.h>

// ShufflePatches: B=32, C=3, H=W=512, P=16 -> grid 32x32 = 1024 patches/image.
// out[b, c, oh*16+p, ow*16+q] = x[b, c, sh*16+p, sw*16+q]
//   where s = perm[b, oh*32+ow], sh = s>>5, sw = s&31.
// Pure memory-bound gather: 100.66 MB read + 100.66 MB write.

__global__ __launch_bounds__(256) void ShufflePatches_45878840656651_kernel(
    const float4* __restrict__ in,   // x as float4, 6291456 elements
    const int*    __restrict__ perm, // (32, 1024)
    float4*       __restrict__ out,
    int total4)                      // 6291456
{
    int idx    = blockIdx.x * blockDim.x + threadIdx.x;
    int stride = gridDim.x * blockDim.x;
    for (int t = idx; t < total4; t += stride) {
        // Decompose output float4 index: t = ((bc*512 + y)*128 + x4)
        int x4  = t & 127;         // float4 column within row (W/4 = 128)
        int row = t >> 7;          // bc*512 + y
        int y   = row & 511;
        int bc  = row >> 9;        // b*3 + c
        int b   = bc / 3;          // compiler emits magic-mul

        int oh = y  >> 4, p  = y  & 15;
        int ow = x4 >> 2, q4 = x4 & 3;

        int j = (oh << 5) | ow;            // patch index, gh-major
        int s = perm[(b << 10) + j];       // source patch
        int sh = s >> 5;
        int sw = s & 31;

        int src = ((bc << 9) + (sh << 4) + p) * 128 + (sw << 2) + q4;
        out[t] = in[src];
    }
}

extern "C" void kernel_launch(void* const* d_in, const int* in_sizes, int n_in,
                              void* d_out, int out_size, void* d_ws, size_t ws_size,
                              hipStream_t stream) {
    const float4* x    = (const float4*)d_in[0];
    const int*    perm = (const int*)d_in[1];
    float4*       out  = (float4*)d_out;

    int total4 = out_size / 4;  // 25165824 / 4 = 6291456
    int threads = 256;
    int blocks = 2048;          // 256 CUs x 8 blocks/CU; grid-stride covers the rest

    ShufflePatches_45878840656651_kernel<<<blocks, threads, 0, stream>>>(
        x, perm, out, total4);
}